// Round 2
// baseline (2839.975 us; speedup 1.0000x reference)
//
#include <hip/hip_runtime.h>
#include <math.h>

#define N_Q 1024
#define M_P 100000
#define D_  256
#define K_  7
#define QT  32
#define MCHUNKS 32
#define CHUNK 3125          // 100000 / 32 exactly
#define NIT 13              // ceil(3125/256)
#define EPSN 1e-8f

// workspace layout (float indices)
#define WS_QN 0             // N*D = 262144  (normalized queries)
#define WS_PA 262144        // M  (pinv * exp(+lam*pt))
#define WS_PB 362144        // M  (pinv * exp(-lam*pt))
#define WS_QA 462144        // N  (exp(-lam*qt))
#define WS_QB 463168        // N  (exp(+lam*qt))
#define WS_CV 464192        // N*MCHUNKS*7 candidate values
#define WS_CI 693568        // N*MCHUNKS*7 candidate indices (int)
#define WS_FI 922944        // N*7 final indices (int)

__device__ inline float waveReduceSum(float v){
    #pragma unroll
    for (int o = 32; o > 0; o >>= 1) v += __shfl_xor(v, o, 64);
    return v;
}

// ---- normalize queries, precompute query exp factors ----
__global__ void prep_query(const float* __restrict__ q, const float* __restrict__ qt,
                           const float* __restrict__ lam_p, float* __restrict__ ws){
    int row  = blockIdx.x * 4 + (threadIdx.x >> 6);
    int lane = threadIdx.x & 63;
    if (row >= N_Q) return;
    const float4* q4 = (const float4*)q;
    float4 v = q4[(size_t)row * 64 + lane];
    float ss = v.x*v.x + v.y*v.y + v.z*v.z + v.w*v.w;
    ss = waveReduceSum(ss);
    float inv = 1.0f / fmaxf(sqrtf(ss), EPSN);
    float4 o; o.x = v.x*inv; o.y = v.y*inv; o.z = v.z*inv; o.w = v.w*inv;
    ((float4*)(ws + WS_QN))[(size_t)row * 64 + lane] = o;
    if (lane == 0){
        float lam = lam_p[0];
        float t = qt[row];
        ws[WS_QA + row] = __expf(-lam * t);
        ws[WS_QB + row] = __expf( lam * t);
    }
}

// ---- pool inverse norms folded with time exp factors ----
__global__ void prep_pool(const float* __restrict__ p, const float* __restrict__ pt,
                          const float* __restrict__ lam_p, float* __restrict__ ws){
    int row  = blockIdx.x * 4 + (threadIdx.x >> 6);
    int lane = threadIdx.x & 63;
    if (row >= M_P) return;
    const float4* p4 = (const float4*)p;
    float4 v = p4[(size_t)row * 64 + lane];
    float ss = v.x*v.x + v.y*v.y + v.z*v.z + v.w*v.w;
    ss = waveReduceSum(ss);
    float pinv = 1.0f / fmaxf(sqrtf(ss), EPSN);
    if (lane == 0){
        float lam = lam_p[0];
        float t = pt[row];
        ws[WS_PA + row] = pinv * __expf( lam * t);
        ws[WS_PB + row] = pinv * __expf(-lam * t);
    }
}

// ---- main scores + per-chunk top-7 ----
__launch_bounds__(256, 3)
__global__ void scores_topk(const float* __restrict__ pool, const float* __restrict__ ptime,
                            const float* __restrict__ qtime, float* __restrict__ ws){
    __shared__ float4 qt4[QT][64];        // 32 KB query tile (normalized)
    __shared__ float  sc[16][257];        // 16.4 KB score slab (half the queries at a time)
    __shared__ float  sQT[QT], sQA[QT], sQB[QT];
    __shared__ float  t7v[QT * 7];
    __shared__ int    t7i[QT * 7];

    int tid   = threadIdx.x;
    int mchunk = blockIdx.x;
    int qbase  = blockIdx.y * QT;

    const float4* qn4 = (const float4*)(ws + WS_QN);
    #pragma unroll
    for (int i = 0; i < 8; ++i){
        int idx = tid + i * 256;
        int r = idx >> 6, c = idx & 63;
        qt4[r][c] = qn4[(size_t)(qbase + r) * 64 + c];
    }
    if (tid < QT){
        sQT[tid] = qtime[qbase + tid];
        sQA[tid] = ws[WS_QA + qbase + tid];
        sQB[tid] = ws[WS_QB + qbase + tid];
    }
    if (tid < QT * 7){ t7v[tid] = -INFINITY; t7i[tid] = 0; }
    __syncthreads();

    int chunk_start = mchunk * CHUNK;
    const float4* p4 = (const float4*)pool;

    for (int it = 0; it < NIT; ++it){
        int li = it * 256 + tid;
        bool valid = li < CHUNK;
        int m  = chunk_start + li;
        int mc = valid ? m : (M_P - 1);

        float acc[QT];
        #pragma unroll
        for (int q = 0; q < QT; ++q) acc[q] = 0.0f;

        const float4* prow = p4 + (size_t)mc * 64;
        #pragma unroll 2
        for (int dd = 0; dd < 64; ++dd){
            float4 pv = prow[dd];
            #pragma unroll
            for (int q = 0; q < QT; ++q){
                float4 qv = qt4[q][dd];     // wave-uniform broadcast read
                acc[q] = fmaf(pv.x, qv.x, fmaf(pv.y, qv.y,
                         fmaf(pv.z, qv.z, fmaf(pv.w, qv.w, acc[q]))));
            }
        }

        float pt = ptime[mc];
        float pa = ws[WS_PA + mc];
        float pb = ws[WS_PB + mc];
        int base_m = chunk_start + it * 256;

        #pragma unroll
        for (int h = 0; h < 2; ++h){
            #pragma unroll
            for (int qq = 0; qq < 16; ++qq){
                int q = h * 16 + qq;
                float f = (sQT[q] > pt) ? (sQA[q] * pa) : (sQB[q] * pb);
                sc[qq][tid] = valid ? acc[q] * f : -INFINITY;
            }
            __syncthreads();
            if (tid < 16){
                int q = h * 16 + tid;
                float thr = t7v[q * 7 + 6];
                for (int j = 0; j < 256; ++j){
                    float v = sc[tid][j];
                    if (v > thr){
                        int mi = base_m + j;
                        int pp = 6;
                        while (pp > 0 && t7v[q * 7 + pp - 1] < v){
                            t7v[q * 7 + pp] = t7v[q * 7 + pp - 1];
                            t7i[q * 7 + pp] = t7i[q * 7 + pp - 1];
                            --pp;
                        }
                        t7v[q * 7 + pp] = v;
                        t7i[q * 7 + pp] = mi;
                        thr = t7v[q * 7 + 6];
                    }
                }
            }
            __syncthreads();
        }
    }

    if (tid < QT * 7){
        int q = tid / 7, j = tid % 7;
        int n = qbase + q;
        size_t off = ((size_t)n * MCHUNKS + mchunk) * 7 + j;
        ws[WS_CV + off] = t7v[tid];
        ((int*)ws)[WS_CI + off] = t7i[tid];
    }
}

// ---- merge 32 chunks * 7 candidates -> final top-7 per query ----
__global__ void merge_topk(float* __restrict__ ws){
    int n = blockIdx.x * 256 + threadIdx.x;
    if (n >= N_Q) return;
    float bv[7]; int bi[7];
    #pragma unroll
    for (int i = 0; i < 7; ++i){ bv[i] = -INFINITY; bi[i] = 0; }
    const float* cv = ws + WS_CV + (size_t)n * (MCHUNKS * 7);
    const int*   ci = (const int*)ws + WS_CI + (size_t)n * (MCHUNKS * 7);
    for (int c = 0; c < MCHUNKS * 7; ++c){
        float v = cv[c]; int id = ci[c];
        if (v > bv[6]){
            int p = 6;
            while (p > 0 && bv[p - 1] < v){ bv[p] = bv[p-1]; bi[p] = bi[p-1]; --p; }
            bv[p] = v; bi[p] = id;
        }
    }
    int* fi = (int*)ws + WS_FI + n * 7;
    #pragma unroll
    for (int i = 0; i < 7; ++i) fi[i] = bi[i];
}

// ---- gather demos, h = demos @ W, GCN chain, fused, anomaly score ----
__launch_bounds__(256, 4)
__global__ void fusion(const float* __restrict__ qemb, const float* __restrict__ pool,
                       const float* __restrict__ W, const float* __restrict__ b,
                       const float* __restrict__ ws, float* __restrict__ out){
    __shared__ float dem[7][256];
    __shared__ float red[3][4];
    __shared__ int   sidx[7];
    int n = blockIdx.x, tid = threadIdx.x;
    if (tid < 7) sidx[tid] = ((const int*)ws)[WS_FI + n * 7 + tid];
    __syncthreads();
    #pragma unroll
    for (int k = 0; k < 7; ++k)
        dem[k][tid] = pool[(size_t)sidx[k] * D_ + tid];
    __syncthreads();

    float h[7];
    #pragma unroll
    for (int k = 0; k < 7; ++k) h[k] = 0.0f;
    for (int e = 0; e < D_; ++e){
        float w = W[(size_t)e * D_ + tid];    // coalesced column read
        #pragma unroll
        for (int k = 0; k < 7; ++k) h[k] = fmaf(dem[k][e], w, h[k]);
    }
    // chain weights: h0*(1+1/sqrt2) + h1..h5*1 + h6*0.5, then /7, then +b
    const float c0 = 1.0f + 0.70710678f;
    float fused = h[0]*c0 + h[1] + h[2] + h[3] + h[4] + h[5] + h[6]*0.5f;
    fused = fused * (1.0f / 7.0f) + b[tid];

    float qn_d = ws[WS_QN + (size_t)n * D_ + tid];
    float q_d  = qemb[(size_t)n * D_ + tid];
    float s_ff = fused * fused;
    float s_qf = qn_d * fused;
    float dq   = q_d - fused;
    float s_dd = dq * dq;
    s_ff = waveReduceSum(s_ff);
    s_qf = waveReduceSum(s_qf);
    s_dd = waveReduceSum(s_dd);
    int wv = tid >> 6, ln = tid & 63;
    if (ln == 0){ red[0][wv] = s_ff; red[1][wv] = s_qf; red[2][wv] = s_dd; }
    __syncthreads();
    if (tid == 0){
        float ff  = red[0][0] + red[0][1] + red[0][2] + red[0][3];
        float qf  = red[1][0] + red[1][1] + red[1][2] + red[1][3];
        float dd2 = red[2][0] + red[2][1] + red[2][2] + red[2][3];
        float cosv = qf / fmaxf(sqrtf(ff), EPSN);
        float l2   = sqrtf(dd2);
        out[n] = 0.6f * (1.0f - cosv) + 0.4f * l2;
    }
}

extern "C" void kernel_launch(void* const* d_in, const int* in_sizes, int n_in,
                              void* d_out, int out_size, void* d_ws, size_t ws_size,
                              hipStream_t stream){
    const float* qemb  = (const float*)d_in[0];
    const float* qtime = (const float*)d_in[1];
    const float* pool  = (const float*)d_in[2];
    const float* ptime = (const float*)d_in[3];
    const float* lam   = (const float*)d_in[4];
    const float* W     = (const float*)d_in[5];
    const float* b     = (const float*)d_in[6];
    float* out = (float*)d_out;
    float* ws  = (float*)d_ws;

    prep_query<<<N_Q / 4, 256, 0, stream>>>(qemb, qtime, lam, ws);
    prep_pool<<<M_P / 4, 256, 0, stream>>>(pool, ptime, lam, ws);
    scores_topk<<<dim3(MCHUNKS, N_Q / QT), 256, 0, stream>>>(pool, ptime, qtime, ws);
    merge_topk<<<N_Q / 256, 256, 0, stream>>>(ws);
    fusion<<<N_Q, 256, 0, stream>>>(qemb, pool, W, b, ws, out);
}

// Round 3
// 1570.986 us; speedup vs baseline: 1.8078x; 1.8078x over previous
//
#include <hip/hip_runtime.h>
#include <math.h>

#define N_Q 1024
#define M_P 100000
#define D_  256
#define K_  7
#define QT  32
#define MCHUNKS 16
#define CHUNK 6250          // 100000 / 16 exactly
#define NIT 25              // ceil(6250/256)
#define EPSN 1e-8f

// workspace layout (float indices)
#define WS_QN 0             // N*D = 262144  (normalized queries, f32)
#define WS_PA 262144        // M  (pinv * exp(+lam*pt))
#define WS_PB 362144        // M  (pinv * exp(-lam*pt))
#define WS_QA 462144        // N  (exp(-lam*qt))
#define WS_QB 463168        // N  (exp(+lam*qt))
#define WS_CV 464192        // N*MCHUNKS*7 candidate values   (114688)
#define WS_CI 578880        // N*MCHUNKS*7 candidate indices  (114688)
#define WS_FI 693568        // N*7 final indices

__device__ inline float waveReduceSum(float v){
    #pragma unroll
    for (int o = 32; o > 0; o >>= 1) v += __shfl_xor(v, o, 64);
    return v;
}

// ---- normalize queries, precompute query exp factors ----
__global__ void prep_query(const float* __restrict__ q, const float* __restrict__ qt,
                           const float* __restrict__ lam_p, float* __restrict__ ws){
    int row  = blockIdx.x * 4 + (threadIdx.x >> 6);
    int lane = threadIdx.x & 63;
    if (row >= N_Q) return;
    const float4* q4 = (const float4*)q;
    float4 v = q4[(size_t)row * 64 + lane];
    float ss = v.x*v.x + v.y*v.y + v.z*v.z + v.w*v.w;
    ss = waveReduceSum(ss);
    float inv = 1.0f / fmaxf(sqrtf(ss), EPSN);
    float4 o; o.x = v.x*inv; o.y = v.y*inv; o.z = v.z*inv; o.w = v.w*inv;
    ((float4*)(ws + WS_QN))[(size_t)row * 64 + lane] = o;
    if (lane == 0){
        float lam = lam_p[0];
        float t = qt[row];
        ws[WS_QA + row] = __expf(-lam * t);
        ws[WS_QB + row] = __expf( lam * t);
    }
}

// ---- pool inverse norms folded with time exp factors ----
__global__ void prep_pool(const float* __restrict__ p, const float* __restrict__ pt,
                          const float* __restrict__ lam_p, float* __restrict__ ws){
    int row  = blockIdx.x * 4 + (threadIdx.x >> 6);
    int lane = threadIdx.x & 63;
    if (row >= M_P) return;
    const float4* p4 = (const float4*)p;
    float4 v = p4[(size_t)row * 64 + lane];
    float ss = v.x*v.x + v.y*v.y + v.z*v.z + v.w*v.w;
    ss = waveReduceSum(ss);
    float pinv = 1.0f / fmaxf(sqrtf(ss), EPSN);
    if (lane == 0){
        float lam = lam_p[0];
        float t = pt[row];
        ws[WS_PA + row] = pinv * __expf( lam * t);
        ws[WS_PB + row] = pinv * __expf(-lam * t);
    }
}

// ---- main scores + per-chunk top-7, register-blocked 4q x 8m per thread ----
__launch_bounds__(256, 2)
__global__ void scores_topk(const float* __restrict__ pool, const float* __restrict__ ptime,
                            const float* __restrict__ qtime, float* __restrict__ ws){
    // query tile: 32 rows x 67 float4 (row stride 67*16B -> bank offset 3r mod 32,
    // 8 distinct q-rows per read instruction -> conflict-free)
    __shared__ float qtile[QT * 268];     // 34.3 KB
    __shared__ float sc[QT][257];         // 32.9 KB score slab (257 odd -> scan conflict-free)
    __shared__ float sQT[QT], sQA[QT], sQB[QT];
    __shared__ float t7v[QT * 7];
    __shared__ int   t7i[QT * 7];

    int tid    = threadIdx.x;
    int mchunk = blockIdx.x;
    int qbase  = blockIdx.y * QT;

    // load normalized query tile into padded LDS
    const float4* qn4 = (const float4*)(ws + WS_QN);
    float4* qt4 = (float4*)qtile;
    #pragma unroll
    for (int i = 0; i < 8; ++i){
        int idx = tid + i * 256;          // 0..2047
        int r = idx >> 6, c = idx & 63;
        qt4[r * 67 + c] = qn4[(size_t)(qbase + r) * 64 + c];
    }
    if (tid < QT){
        sQT[tid] = qtime[qbase + tid];
        sQA[tid] = ws[WS_QA + qbase + tid];
        sQB[tid] = ws[WS_QB + qbase + tid];
    }
    if (tid < QT * 7){ t7v[tid] = -INFINITY; t7i[tid] = 0; }
    __syncthreads();

    int qg = tid & 7;                     // 8 groups x 4 queries = 32 q
    int mg = tid >> 3;                    // 32 groups x 8 rows   = 256 m per iter
    int chunk_start = mchunk * CHUNK;
    const float4* p4 = (const float4*)pool;

    for (int it = 0; it < NIT; ++it){
        int mb = it * 256 + mg * 8;       // thread's local base row
        int rows[8];
        #pragma unroll
        for (int i = 0; i < 8; ++i){
            int li = mb + i;
            rows[i] = (li < CHUNK) ? (chunk_start + li) : (M_P - 1);
        }

        float acc0[8], acc1[8], acc2[8], acc3[8];
        #pragma unroll
        for (int i = 0; i < 8; ++i){ acc0[i]=0.f; acc1[i]=0.f; acc2[i]=0.f; acc3[i]=0.f; }

        #pragma unroll 1
        for (int dd = 0; dd < 64; ++dd){
            float4 qv0 = qt4[(qg * 4 + 0) * 67 + dd];
            float4 qv1 = qt4[(qg * 4 + 1) * 67 + dd];
            float4 qv2 = qt4[(qg * 4 + 2) * 67 + dd];
            float4 qv3 = qt4[(qg * 4 + 3) * 67 + dd];
            #pragma unroll
            for (int i = 0; i < 8; ++i){
                float4 pv = p4[(size_t)rows[i] * 64 + dd];
                acc0[i] = fmaf(pv.x,qv0.x,fmaf(pv.y,qv0.y,fmaf(pv.z,qv0.z,fmaf(pv.w,qv0.w,acc0[i]))));
                acc1[i] = fmaf(pv.x,qv1.x,fmaf(pv.y,qv1.y,fmaf(pv.z,qv1.z,fmaf(pv.w,qv1.w,acc1[i]))));
                acc2[i] = fmaf(pv.x,qv2.x,fmaf(pv.y,qv2.y,fmaf(pv.z,qv2.z,fmaf(pv.w,qv2.w,acc2[i]))));
                acc3[i] = fmaf(pv.x,qv3.x,fmaf(pv.y,qv3.y,fmaf(pv.z,qv3.z,fmaf(pv.w,qv3.w,acc3[i]))));
            }
        }

        // time-weight and write to slab
        #pragma unroll
        for (int i = 0; i < 8; ++i){
            int li = mb + i;
            bool valid = li < CHUNK;
            int r = rows[i];
            float pt = ptime[r];
            float pa = ws[WS_PA + r];
            float pb = ws[WS_PB + r];
            int q0 = qg * 4;
            float f0 = (sQT[q0+0] > pt) ? (sQA[q0+0]*pa) : (sQB[q0+0]*pb);
            float f1 = (sQT[q0+1] > pt) ? (sQA[q0+1]*pa) : (sQB[q0+1]*pb);
            float f2 = (sQT[q0+2] > pt) ? (sQA[q0+2]*pa) : (sQB[q0+2]*pb);
            float f3 = (sQT[q0+3] > pt) ? (sQA[q0+3]*pa) : (sQB[q0+3]*pb);
            int ml = mg * 8 + i;
            sc[q0+0][ml] = valid ? acc0[i]*f0 : -INFINITY;
            sc[q0+1][ml] = valid ? acc1[i]*f1 : -INFINITY;
            sc[q0+2][ml] = valid ? acc2[i]*f2 : -INFINITY;
            sc[q0+3][ml] = valid ? acc3[i]*f3 : -INFINITY;
        }
        __syncthreads();

        // 32 parallel per-query scans (one lane per query)
        if (tid < QT){
            int q = tid;
            float thr = t7v[q * 7 + 6];
            int base_m = chunk_start + it * 256;
            for (int j = 0; j < 256; ++j){
                float v = sc[q][j];
                if (v > thr){
                    int mi = base_m + j;
                    int pp = 6;
                    while (pp > 0 && t7v[q * 7 + pp - 1] < v){
                        t7v[q * 7 + pp] = t7v[q * 7 + pp - 1];
                        t7i[q * 7 + pp] = t7i[q * 7 + pp - 1];
                        --pp;
                    }
                    t7v[q * 7 + pp] = v;
                    t7i[q * 7 + pp] = mi;
                    thr = t7v[q * 7 + 6];
                }
            }
        }
        __syncthreads();
    }

    if (tid < QT * 7){
        int q = tid / 7, j = tid % 7;
        int n = qbase + q;
        size_t off = ((size_t)n * MCHUNKS + mchunk) * 7 + j;
        ws[WS_CV + off] = t7v[tid];
        ((int*)ws)[WS_CI + off] = t7i[tid];
    }
}

// ---- merge MCHUNKS * 7 candidates -> final top-7 per query ----
__global__ void merge_topk(float* __restrict__ ws){
    int n = blockIdx.x * 256 + threadIdx.x;
    if (n >= N_Q) return;
    float bv[7]; int bi[7];
    #pragma unroll
    for (int i = 0; i < 7; ++i){ bv[i] = -INFINITY; bi[i] = 0; }
    const float* cv = ws + WS_CV + (size_t)n * (MCHUNKS * 7);
    const int*   ci = (const int*)ws + WS_CI + (size_t)n * (MCHUNKS * 7);
    for (int c = 0; c < MCHUNKS * 7; ++c){
        float v = cv[c]; int id = ci[c];
        if (v > bv[6]){
            int p = 6;
            while (p > 0 && bv[p - 1] < v){ bv[p] = bv[p-1]; bi[p] = bi[p-1]; --p; }
            bv[p] = v; bi[p] = id;
        }
    }
    int* fi = (int*)ws + WS_FI + n * 7;
    #pragma unroll
    for (int i = 0; i < 7; ++i) fi[i] = bi[i];
}

// ---- gather demos, h = demos @ W, GCN chain, fused, anomaly score ----
__launch_bounds__(256, 4)
__global__ void fusion(const float* __restrict__ qemb, const float* __restrict__ pool,
                       const float* __restrict__ W, const float* __restrict__ b,
                       const float* __restrict__ ws, float* __restrict__ out){
    __shared__ float dem[7][256];
    __shared__ float red[3][4];
    __shared__ int   sidx[7];
    int n = blockIdx.x, tid = threadIdx.x;
    if (tid < 7) sidx[tid] = ((const int*)ws)[WS_FI + n * 7 + tid];
    __syncthreads();
    #pragma unroll
    for (int k = 0; k < 7; ++k)
        dem[k][tid] = pool[(size_t)sidx[k] * D_ + tid];
    __syncthreads();

    float h[7];
    #pragma unroll
    for (int k = 0; k < 7; ++k) h[k] = 0.0f;
    for (int e = 0; e < D_; ++e){
        float w = W[(size_t)e * D_ + tid];    // coalesced column read
        #pragma unroll
        for (int k = 0; k < 7; ++k) h[k] = fmaf(dem[k][e], w, h[k]);
    }
    // chain weights: h0*(1+1/sqrt2) + h1..h5*1 + h6*0.5, then /7, then +b
    const float c0 = 1.0f + 0.70710678f;
    float fused = h[0]*c0 + h[1] + h[2] + h[3] + h[4] + h[5] + h[6]*0.5f;
    fused = fused * (1.0f / 7.0f) + b[tid];

    float qn_d = ws[WS_QN + (size_t)n * D_ + tid];
    float q_d  = qemb[(size_t)n * D_ + tid];
    float s_ff = fused * fused;
    float s_qf = qn_d * fused;
    float dq   = q_d - fused;
    float s_dd = dq * dq;
    s_ff = waveReduceSum(s_ff);
    s_qf = waveReduceSum(s_qf);
    s_dd = waveReduceSum(s_dd);
    int wv = tid >> 6, ln = tid & 63;
    if (ln == 0){ red[0][wv] = s_ff; red[1][wv] = s_qf; red[2][wv] = s_dd; }
    __syncthreads();
    if (tid == 0){
        float ff  = red[0][0] + red[0][1] + red[0][2] + red[0][3];
        float qf  = red[1][0] + red[1][1] + red[1][2] + red[1][3];
        float dd2 = red[2][0] + red[2][1] + red[2][2] + red[2][3];
        float cosv = qf / fmaxf(sqrtf(ff), EPSN);
        float l2   = sqrtf(dd2);
        out[n] = 0.6f * (1.0f - cosv) + 0.4f * l2;
    }
}

extern "C" void kernel_launch(void* const* d_in, const int* in_sizes, int n_in,
                              void* d_out, int out_size, void* d_ws, size_t ws_size,
                              hipStream_t stream){
    const float* qemb  = (const float*)d_in[0];
    const float* qtime = (const float*)d_in[1];
    const float* pool  = (const float*)d_in[2];
    const float* ptime = (const float*)d_in[3];
    const float* lam   = (const float*)d_in[4];
    const float* W     = (const float*)d_in[5];
    const float* b     = (const float*)d_in[6];
    float* out = (float*)d_out;
    float* ws  = (float*)d_ws;

    prep_query<<<N_Q / 4, 256, 0, stream>>>(qemb, qtime, lam, ws);
    prep_pool<<<M_P / 4, 256, 0, stream>>>(pool, ptime, lam, ws);
    scores_topk<<<dim3(MCHUNKS, N_Q / QT), 256, 0, stream>>>(pool, ptime, qtime, ws);
    merge_topk<<<N_Q / 256, 256, 0, stream>>>(ws);
    fusion<<<N_Q, 256, 0, stream>>>(qemb, pool, W, b, ws, out);
}

// Round 4
// 1559.705 us; speedup vs baseline: 1.8208x; 1.0072x over previous
//
#include <hip/hip_runtime.h>
#include <math.h>

#define N_Q 1024
#define M_P 100000
#define D_  256
#define K_  7
#define QT  32
#define MCHUNKS 16
#define CHUNK 6250          // 100000 / 16 exactly
#define NIT 25              // ceil(6250/256)
#define EPSN 1e-8f

// workspace layout (float indices)
#define WS_QN 0             // N*D = 262144  (normalized queries, f32)
#define WS_PA 262144        // M  (pinv * exp(+lam*pt))
#define WS_PB 362144        // M  (pinv * exp(-lam*pt))
#define WS_QA 462144        // N  (exp(-lam*qt))
#define WS_QB 463168        // N  (exp(+lam*qt))
#define WS_CV 464192        // N*MCHUNKS*7 candidate values   (114688)
#define WS_CI 578880        // N*MCHUNKS*7 candidate indices  (114688)
#define WS_FI 693568        // N*7 final indices

__device__ inline float waveReduceSum(float v){
    #pragma unroll
    for (int o = 32; o > 0; o >>= 1) v += __shfl_xor(v, o, 64);
    return v;
}

// ---- normalize queries, precompute query exp factors ----
__global__ void prep_query(const float* __restrict__ q, const float* __restrict__ qt,
                           const float* __restrict__ lam_p, float* __restrict__ ws){
    int row  = blockIdx.x * 4 + (threadIdx.x >> 6);
    int lane = threadIdx.x & 63;
    if (row >= N_Q) return;
    const float4* q4 = (const float4*)q;
    float4 v = q4[(size_t)row * 64 + lane];
    float ss = v.x*v.x + v.y*v.y + v.z*v.z + v.w*v.w;
    ss = waveReduceSum(ss);
    float inv = 1.0f / fmaxf(sqrtf(ss), EPSN);
    float4 o; o.x = v.x*inv; o.y = v.y*inv; o.z = v.z*inv; o.w = v.w*inv;
    ((float4*)(ws + WS_QN))[(size_t)row * 64 + lane] = o;
    if (lane == 0){
        float lam = lam_p[0];
        float t = qt[row];
        ws[WS_QA + row] = __expf(-lam * t);
        ws[WS_QB + row] = __expf( lam * t);
    }
}

// ---- pool inverse norms folded with time exp factors ----
__global__ void prep_pool(const float* __restrict__ p, const float* __restrict__ pt,
                          const float* __restrict__ lam_p, float* __restrict__ ws){
    int row  = blockIdx.x * 4 + (threadIdx.x >> 6);
    int lane = threadIdx.x & 63;
    if (row >= M_P) return;
    const float4* p4 = (const float4*)p;
    float4 v = p4[(size_t)row * 64 + lane];
    float ss = v.x*v.x + v.y*v.y + v.z*v.z + v.w*v.w;
    ss = waveReduceSum(ss);
    float pinv = 1.0f / fmaxf(sqrtf(ss), EPSN);
    if (lane == 0){
        float lam = lam_p[0];
        float t = pt[row];
        ws[WS_PA + row] = pinv * __expf( lam * t);
        ws[WS_PB + row] = pinv * __expf(-lam * t);
    }
}

// ---- main scores + per-chunk top-7, register-blocked 4q x 8m per thread ----
// Thread qg owns queries {qg, qg+8, qg+16, qg+24}: the 8 rows read
// concurrently (fixed k across lanes) are consecutive {8k..8k+7};
// row stride 268 dwords => quad-starts 12*r mod 32 all distinct -> conflict-free.
__launch_bounds__(256, 2)
__global__ void scores_topk(const float* __restrict__ pool, const float* __restrict__ ptime,
                            const float* __restrict__ qtime, float* __restrict__ ws){
    __shared__ float qtile[QT * 268];     // 34.3 KB, row stride 67 float4
    __shared__ float sc[QT][257];         // 32.9 KB score slab
    __shared__ float sQT[QT], sQA[QT], sQB[QT];
    __shared__ float t7v[QT * 7];
    __shared__ int   t7i[QT * 7];

    int tid    = threadIdx.x;
    int mchunk = blockIdx.x;
    int qbase  = blockIdx.y * QT;

    const float4* qn4 = (const float4*)(ws + WS_QN);
    float4* qt4 = (float4*)qtile;
    #pragma unroll
    for (int i = 0; i < 8; ++i){
        int idx = tid + i * 256;          // 0..2047
        int r = idx >> 6, c = idx & 63;
        qt4[r * 67 + c] = qn4[(size_t)(qbase + r) * 64 + c];
    }
    if (tid < QT){
        sQT[tid] = qtime[qbase + tid];
        sQA[tid] = ws[WS_QA + qbase + tid];
        sQB[tid] = ws[WS_QB + qbase + tid];
    }
    if (tid < QT * 7){ t7v[tid] = -INFINITY; t7i[tid] = 0; }
    __syncthreads();

    int qg = tid & 7;                     // query set {qg+8k}, k=0..3
    int mg = tid >> 3;                    // 32 groups x 8 rows = 256 m per iter
    int chunk_start = mchunk * CHUNK;
    const float4* p4 = (const float4*)pool;

    for (int it = 0; it < NIT; ++it){
        int mb = it * 256 + mg * 8;
        int rows[8];
        #pragma unroll
        for (int i = 0; i < 8; ++i){
            int li = mb + i;
            rows[i] = (li < CHUNK) ? (chunk_start + li) : (M_P - 1);
        }

        float acc0[8], acc1[8], acc2[8], acc3[8];
        #pragma unroll
        for (int i = 0; i < 8; ++i){ acc0[i]=0.f; acc1[i]=0.f; acc2[i]=0.f; acc3[i]=0.f; }

        #pragma unroll 2
        for (int dd = 0; dd < 64; ++dd){
            float4 qv0 = qt4[(qg +  0) * 67 + dd];
            float4 qv1 = qt4[(qg +  8) * 67 + dd];
            float4 qv2 = qt4[(qg + 16) * 67 + dd];
            float4 qv3 = qt4[(qg + 24) * 67 + dd];
            #pragma unroll
            for (int i = 0; i < 8; ++i){
                float4 pv = p4[(size_t)rows[i] * 64 + dd];
                acc0[i] = fmaf(pv.x,qv0.x,fmaf(pv.y,qv0.y,fmaf(pv.z,qv0.z,fmaf(pv.w,qv0.w,acc0[i]))));
                acc1[i] = fmaf(pv.x,qv1.x,fmaf(pv.y,qv1.y,fmaf(pv.z,qv1.z,fmaf(pv.w,qv1.w,acc1[i]))));
                acc2[i] = fmaf(pv.x,qv2.x,fmaf(pv.y,qv2.y,fmaf(pv.z,qv2.z,fmaf(pv.w,qv2.w,acc2[i]))));
                acc3[i] = fmaf(pv.x,qv3.x,fmaf(pv.y,qv3.y,fmaf(pv.z,qv3.z,fmaf(pv.w,qv3.w,acc3[i]))));
            }
        }

        // time-weight and write to slab (write pattern 2-way aliased = free)
        #pragma unroll
        for (int i = 0; i < 8; ++i){
            int li = mb + i;
            bool valid = li < CHUNK;
            int r = rows[i];
            float pt = ptime[r];
            float pa = ws[WS_PA + r];
            float pb = ws[WS_PB + r];
            float f0 = (sQT[qg+ 0] > pt) ? (sQA[qg+ 0]*pa) : (sQB[qg+ 0]*pb);
            float f1 = (sQT[qg+ 8] > pt) ? (sQA[qg+ 8]*pa) : (sQB[qg+ 8]*pb);
            float f2 = (sQT[qg+16] > pt) ? (sQA[qg+16]*pa) : (sQB[qg+16]*pb);
            float f3 = (sQT[qg+24] > pt) ? (sQA[qg+24]*pa) : (sQB[qg+24]*pb);
            int ml = mg * 8 + i;
            sc[qg+ 0][ml] = valid ? acc0[i]*f0 : -INFINITY;
            sc[qg+ 8][ml] = valid ? acc1[i]*f1 : -INFINITY;
            sc[qg+16][ml] = valid ? acc2[i]*f2 : -INFINITY;
            sc[qg+24][ml] = valid ? acc3[i]*f3 : -INFINITY;
        }
        __syncthreads();

        // 32 parallel per-query scans (lane l scans row l: bank l+j, conflict-free)
        if (tid < QT){
            int q = tid;
            float thr = t7v[q * 7 + 6];
            int base_m = chunk_start + it * 256;
            for (int j = 0; j < 256; ++j){
                float v = sc[q][j];
                if (v > thr){
                    int mi = base_m + j;
                    int pp = 6;
                    while (pp > 0 && t7v[q * 7 + pp - 1] < v){
                        t7v[q * 7 + pp] = t7v[q * 7 + pp - 1];
                        t7i[q * 7 + pp] = t7i[q * 7 + pp - 1];
                        --pp;
                    }
                    t7v[q * 7 + pp] = v;
                    t7i[q * 7 + pp] = mi;
                    thr = t7v[q * 7 + 6];
                }
            }
        }
        __syncthreads();
    }

    if (tid < QT * 7){
        int q = tid / 7, j = tid % 7;
        int n = qbase + q;
        size_t off = ((size_t)n * MCHUNKS + mchunk) * 7 + j;
        ws[WS_CV + off] = t7v[tid];
        ((int*)ws)[WS_CI + off] = t7i[tid];
    }
}

// ---- merge MCHUNKS * 7 candidates -> final top-7 per query ----
__global__ void merge_topk(float* __restrict__ ws){
    int n = blockIdx.x * 256 + threadIdx.x;
    if (n >= N_Q) return;
    float bv[7]; int bi[7];
    #pragma unroll
    for (int i = 0; i < 7; ++i){ bv[i] = -INFINITY; bi[i] = 0; }
    const float* cv = ws + WS_CV + (size_t)n * (MCHUNKS * 7);
    const int*   ci = (const int*)ws + WS_CI + (size_t)n * (MCHUNKS * 7);
    for (int c = 0; c < MCHUNKS * 7; ++c){
        float v = cv[c]; int id = ci[c];
        if (v > bv[6]){
            int p = 6;
            while (p > 0 && bv[p - 1] < v){ bv[p] = bv[p-1]; bi[p] = bi[p-1]; --p; }
            bv[p] = v; bi[p] = id;
        }
    }
    int* fi = (int*)ws + WS_FI + n * 7;
    #pragma unroll
    for (int i = 0; i < 7; ++i) fi[i] = bi[i];
}

// ---- gather demos, h = demos @ W, GCN chain, fused, anomaly score ----
__launch_bounds__(256, 4)
__global__ void fusion(const float* __restrict__ qemb, const float* __restrict__ pool,
                       const float* __restrict__ W, const float* __restrict__ b,
                       const float* __restrict__ ws, float* __restrict__ out){
    __shared__ float dem[7][256];
    __shared__ float red[3][4];
    __shared__ int   sidx[7];
    int n = blockIdx.x, tid = threadIdx.x;
    if (tid < 7) sidx[tid] = ((const int*)ws)[WS_FI + n * 7 + tid];
    __syncthreads();
    #pragma unroll
    for (int k = 0; k < 7; ++k)
        dem[k][tid] = pool[(size_t)sidx[k] * D_ + tid];
    __syncthreads();

    float h[7];
    #pragma unroll
    for (int k = 0; k < 7; ++k) h[k] = 0.0f;
    for (int e = 0; e < D_; ++e){
        float w = W[(size_t)e * D_ + tid];    // coalesced column read
        #pragma unroll
        for (int k = 0; k < 7; ++k) h[k] = fmaf(dem[k][e], w, h[k]);
    }
    // chain weights: h0*(1+1/sqrt2) + h1..h5*1 + h6*0.5, then /7, then +b
    const float c0 = 1.0f + 0.70710678f;
    float fused = h[0]*c0 + h[1] + h[2] + h[3] + h[4] + h[5] + h[6]*0.5f;
    fused = fused * (1.0f / 7.0f) + b[tid];

    float qn_d = ws[WS_QN + (size_t)n * D_ + tid];
    float q_d  = qemb[(size_t)n * D_ + tid];
    float s_ff = fused * fused;
    float s_qf = qn_d * fused;
    float dq   = q_d - fused;
    float s_dd = dq * dq;
    s_ff = waveReduceSum(s_ff);
    s_qf = waveReduceSum(s_qf);
    s_dd = waveReduceSum(s_dd);
    int wv = tid >> 6, ln = tid & 63;
    if (ln == 0){ red[0][wv] = s_ff; red[1][wv] = s_qf; red[2][wv] = s_dd; }
    __syncthreads();
    if (tid == 0){
        float ff  = red[0][0] + red[0][1] + red[0][2] + red[0][3];
        float qf  = red[1][0] + red[1][1] + red[1][2] + red[1][3];
        float dd2 = red[2][0] + red[2][1] + red[2][2] + red[2][3];
        float cosv = qf / fmaxf(sqrtf(ff), EPSN);
        float l2   = sqrtf(dd2);
        out[n] = 0.6f * (1.0f - cosv) + 0.4f * l2;
    }
}

extern "C" void kernel_launch(void* const* d_in, const int* in_sizes, int n_in,
                              void* d_out, int out_size, void* d_ws, size_t ws_size,
                              hipStream_t stream){
    const float* qemb  = (const float*)d_in[0];
    const float* qtime = (const float*)d_in[1];
    const float* pool  = (const float*)d_in[2];
    const float* ptime = (const float*)d_in[3];
    const float* lam   = (const float*)d_in[4];
    const float* W     = (const float*)d_in[5];
    const float* b     = (const float*)d_in[6];
    float* out = (float*)d_out;
    float* ws  = (float*)d_ws;

    prep_query<<<N_Q / 4, 256, 0, stream>>>(qemb, qtime, lam, ws);
    prep_pool<<<M_P / 4, 256, 0, stream>>>(pool, ptime, lam, ws);
    scores_topk<<<dim3(MCHUNKS, N_Q / QT), 256, 0, stream>>>(pool, ptime, qtime, ws);
    merge_topk<<<N_Q / 256, 256, 0, stream>>>(ws);
    fusion<<<N_Q, 256, 0, stream>>>(qemb, pool, W, b, ws, out);
}

// Round 5
// 493.008 us; speedup vs baseline: 5.7605x; 3.1637x over previous
//
#include <hip/hip_runtime.h>
#include <math.h>

#define N_Q 1024
#define M_P 100000
#define D_  256
#define EPSN 1e-8f
#define NCH 32            // pool chunks
#define CHL 3125          // rows per chunk
#define NBATCH 49         // 49 batches * 4 m-tiles * 16 rows = 3136 (11 pad rows)
#define NQT 16            // query tiles of 64

typedef unsigned int uint_t;
typedef unsigned short ushort_t;
typedef __attribute__((ext_vector_type(8))) short short8;
typedef __attribute__((ext_vector_type(4))) float f32x4;

// ---- ws byte offsets (total ~53.7 MB) ----
#define OFF_QN    ((size_t)0)          // f32 [1024][256]
#define OFF_QA    ((size_t)1048576)    // f32 [1024]
#define OFF_QB    ((size_t)1052672)    // f32 [1024]
#define OFF_PAB   ((size_t)1056768)    // f32x2 [100000] (pa,pb) + pad
#define OFF_QNB   ((size_t)1857536)    // bf16 [1024][256]
#define OFF_PB16  ((size_t)2381824)    // bf16 [100000][256]
#define OFF_CK    ((size_t)53581824)   // u32 [320][1024] candidate keys
#define OFF_CI    ((size_t)54892544)   // i32 [320][1024] candidate global idx
#define OFF_C16   ((size_t)56203264)   // i32 [16][1024]
#define OFF_FI    ((size_t)56268800)   // i32 [1024][7]

__device__ inline float waveReduceSum(float v){
    #pragma unroll
    for (int o = 32; o > 0; o >>= 1) v += __shfl_xor(v, o, 64);
    return v;
}
__device__ inline ushort_t f2bf(float x){           // RNE f32->bf16
    uint_t u = __float_as_uint(x);
    return (ushort_t)((u + 0x7FFFu + ((u >> 16) & 1u)) >> 16);
}
__device__ inline uint_t umaxu(uint_t a, uint_t b){ return a > b ? a : b; }
__device__ inline uint_t uminu(uint_t a, uint_t b){ return a < b ? a : b; }

// ---- normalize queries -> qn(f32) + qnb(bf16); exp factors ----
__global__ void prep_query(const float* __restrict__ q, const float* __restrict__ qt,
                           const float* __restrict__ lam_p, float* __restrict__ qn,
                           ushort_t* __restrict__ qnb, float* __restrict__ qa,
                           float* __restrict__ qb){
    int row = blockIdx.x * 4 + (threadIdx.x >> 6);
    int lane = threadIdx.x & 63;
    const float4* q4 = (const float4*)q;
    float4 v = q4[(size_t)row * 64 + lane];
    float ss = waveReduceSum(v.x*v.x + v.y*v.y + v.z*v.z + v.w*v.w);
    float inv = 1.0f / fmaxf(sqrtf(ss), EPSN);
    float4 o; o.x = v.x*inv; o.y = v.y*inv; o.z = v.z*inv; o.w = v.w*inv;
    ((float4*)qn)[(size_t)row * 64 + lane] = o;
    ushort4 ob; ob.x = f2bf(o.x); ob.y = f2bf(o.y); ob.z = f2bf(o.z); ob.w = f2bf(o.w);
    ((ushort4*)qnb)[(size_t)row * 64 + lane] = ob;
    if (lane == 0){
        float lam = lam_p[0], t = qt[row];
        qa[row] = expf(-lam * t);
        qb[row] = expf( lam * t);
    }
}

// ---- pool -> poolb(bf16 raw); pab = (pinv*e^{+lam*t}, pinv*e^{-lam*t}) ----
__global__ void prep_pool(const float* __restrict__ p, const float* __restrict__ pt,
                          const float* __restrict__ lam_p, float* __restrict__ pab,
                          ushort_t* __restrict__ poolb){
    int row = blockIdx.x * 4 + (threadIdx.x >> 6);
    int lane = threadIdx.x & 63;
    const float4* p4 = (const float4*)p;
    float4 v = p4[(size_t)row * 64 + lane];
    float ss = waveReduceSum(v.x*v.x + v.y*v.y + v.z*v.z + v.w*v.w);
    float pinv = 1.0f / fmaxf(sqrtf(ss), EPSN);
    ushort4 ob; ob.x = f2bf(v.x); ob.y = f2bf(v.y); ob.z = f2bf(v.z); ob.w = f2bf(v.w);
    ((ushort4*)poolb)[(size_t)row * 64 + lane] = ob;
    if (lane == 0){
        float lam = lam_p[0], t = pt[row];
        ((float2*)pab)[row] = make_float2(pinv * expf(lam * t), pinv * expf(-lam * t));
    }
}

// ---- MFMA scores + register top-k. Pool=A(M), queries=B(N). ----
// C/D: q-col = lane&15, m-row = (lane>>4)*4 + reg  [m89 verified]
__launch_bounds__(256, 2)
__global__ void scores_mfma(const ushort_t* __restrict__ poolb,
                            const ushort_t* __restrict__ qnb,
                            const float* __restrict__ pabf,
                            const float* __restrict__ qaA, const float* __restrict__ qbA,
                            uint_t* __restrict__ ck, int* __restrict__ ci){
    __shared__ uint_t mk[64 * 132];
    int tid = threadIdx.x;
    int w = tid >> 6, l = tid & 63;
    int lr = l & 15, lh = l >> 4;

    int bid = blockIdx.x;
    int xcd = bid & 7, loc = bid >> 3;
    int chunk = xcd * 4 + (loc & 3);    // 4 chunks per XCD -> chunk L2-resident
    int qt = loc >> 2;
    int qbase = qt * 64;
    int chunk_start = chunk * CHL;

    // resident query B-frags: B[k][n=lr] = qn[qbase+16qs+lr][k], 8 contiguous k per reg
    short8 bfr[4][8];
    float qa[4], qb[4];
    #pragma unroll
    for (int qs = 0; qs < 4; ++qs){
        int qrow = qbase + 16*qs + lr;
        #pragma unroll
        for (int ks = 0; ks < 8; ++ks)
            bfr[qs][ks] = *(const short8*)(qnb + (size_t)qrow * 256 + 32*ks + 8*lh);
        qa[qs] = qaA[qrow];
        qb[qs] = qbA[qrow];
    }

    uint_t t[4][8];
    #pragma unroll
    for (int qs = 0; qs < 4; ++qs)
        #pragma unroll
        for (int j = 0; j < 8; ++j) t[qs][j] = 0u;

    const float2* pab = (const float2*)pabf;

    for (int b = 0; b < NBATCH; ++b){
        int mrow = (b * 4 + w) * 16;                 // local m base of this wave's tile
        int lrow = mrow + lr; if (lrow > CHL - 1) lrow = CHL - 1;
        const short8* prow = (const short8*)(poolb + (size_t)(chunk_start + lrow) * 256);
        short8 afr[8];
        #pragma unroll
        for (int ks = 0; ks < 8; ++ks) afr[ks] = prow[ks * 4 + lh];

        long gm0 = (long)chunk_start + mrow + 4*lh;  // epilogue rows (pad-read safe)
        float4 pab01 = *(const float4*)(pab + gm0);
        float4 pab23 = *(const float4*)(pab + gm0 + 2);
        float pa_[4] = {pab01.x, pab01.z, pab23.x, pab23.z};
        float pb_[4] = {pab01.y, pab01.w, pab23.y, pab23.w};

        f32x4 acc[4];
        #pragma unroll
        for (int qs = 0; qs < 4; ++qs) acc[qs] = (f32x4){0.f, 0.f, 0.f, 0.f};
        #pragma unroll
        for (int ks = 0; ks < 8; ++ks)
            #pragma unroll
            for (int qs = 0; qs < 4; ++qs)
                acc[qs] = __builtin_amdgcn_mfma_f32_16x16x32_bf16(afr[ks], bfr[qs][ks], acc[qs], 0, 0, 0);

        #pragma unroll
        for (int r = 0; r < 4; ++r){
            int lm = mrow + 4*lh + r;
            bool valid = lm < CHL;
            uint_t lmkey = 0xFFFFu ^ (uint_t)lm;     // inverted idx: ties -> smaller index
            #pragma unroll
            for (int qs = 0; qs < 4; ++qs){
                float f = fminf(qa[qs] * pa_[r], qb[qs] * pb_[r]);   // pinv*exp(-lam|dt|)
                float s = acc[qs][r] * f;
                uint_t u = __float_as_uint(s);
                u ^= (uint_t)(((int)u) >> 31) | 0x80000000u;         // sortable float
                uint_t key = (u & 0xFFFF0000u) | lmkey;
                key = valid ? key : 0u;
                if (key > t[qs][7]){                                  // rare insert
                    #pragma unroll
                    for (int j = 7; j >= 1; --j)
                        t[qs][j] = umaxu(t[qs][j], uminu(t[qs][j-1], key));
                    t[qs][0] = umaxu(t[qs][0], key);
                }
            }
        }
    }

    // merge 16 strips x top-8 -> per-chunk top-10 per query (once per kernel)
    #pragma unroll
    for (int qs = 0; qs < 4; ++qs){
        int base = (16*qs + lr) * 132 + (w*4 + lh) * 8;
        uint4 lo = make_uint4(t[qs][0], t[qs][1], t[qs][2], t[qs][3]);
        uint4 hi = make_uint4(t[qs][4], t[qs][5], t[qs][6], t[qs][7]);
        *(uint4*)&mk[base] = lo;
        *(uint4*)&mk[base + 4] = hi;
    }
    __syncthreads();
    if (tid < 64){
        uint_t s[10];
        #pragma unroll
        for (int j = 0; j < 10; ++j) s[j] = 0u;
        for (int j = 0; j < 32; ++j){
            uint4 kk = *(const uint4*)&mk[tid * 132 + j * 4];
            uint_t kv[4] = {kk.x, kk.y, kk.z, kk.w};
            #pragma unroll
            for (int e = 0; e < 4; ++e){
                uint_t k = kv[e];
                if (k > s[9]){
                    #pragma unroll
                    for (int jj = 9; jj >= 1; --jj)
                        s[jj] = umaxu(s[jj], uminu(s[jj-1], k));
                    s[0] = umaxu(s[0], k);
                }
            }
        }
        int qg = qbase + tid;
        #pragma unroll
        for (int j = 0; j < 10; ++j){
            uint_t key = s[j];
            int lm = (int)(0xFFFFu ^ (key & 0xFFFFu));
            ck[(size_t)(chunk*10 + j) * 1024 + qg] = key;
            ci[(size_t)(chunk*10 + j) * 1024 + qg] = chunk_start + lm;
        }
    }
}

// ---- global merge: 320 candidates -> top-16 by bf16 key per query ----
__global__ void merge_global(const uint_t* __restrict__ ck, const int* __restrict__ ci,
                             int* __restrict__ c16){
    int q = blockIdx.x * 256 + threadIdx.x;
    uint_t s[16]; int si[16];
    #pragma unroll
    for (int j = 0; j < 16; ++j){ s[j] = 0u; si[j] = 0; }
    for (int c = 0; c < NCH * 10; ++c){
        uint_t k = ck[(size_t)c * 1024 + q];
        int idx   = ci[(size_t)c * 1024 + q];
        if (k > s[15]){
            #pragma unroll
            for (int j = 15; j >= 1; --j){
                bool a = k > s[j-1];
                bool b = k > s[j];
                uint_t ns = a ? s[j-1] : (b ? k : s[j]);
                int nsi   = a ? si[j-1] : (b ? idx : si[j]);
                s[j] = ns; si[j] = nsi;
            }
            bool b0 = k > s[0];
            si[0] = b0 ? idx : si[0];
            s[0]  = b0 ? k : s[0];
        }
    }
    #pragma unroll
    for (int j = 0; j < 16; ++j) c16[(size_t)j * 1024 + q] = si[j];
}

// ---- exact f32 re-rank of 16 candidates -> final top-7 (ref tie semantics) ----
__global__ void rerank(const float* __restrict__ pool, const float* __restrict__ qn,
                       const float* __restrict__ pabf, const float* __restrict__ qaA,
                       const float* __restrict__ qbA, const int* __restrict__ c16,
                       int* __restrict__ fi){
    int n = blockIdx.x, tid = threadIdx.x;
    int w = tid >> 6, l = tid & 63;
    __shared__ float sv[16];
    __shared__ int   sx[16];
    const float4* qn4 = (const float4*)qn;
    const float4* p4  = (const float4*)pool;
    float4 qv = qn4[(size_t)n * 64 + l];
    float qa = qaA[n], qb = qbA[n];
    const float2* pab = (const float2*)pabf;
    for (int c = 0; c < 4; ++c){
        int cand = c16[(size_t)(w*4 + c) * 1024 + n];
        float4 pv = p4[(size_t)cand * 64 + l];
        float d = qv.x*pv.x + qv.y*pv.y + qv.z*pv.z + qv.w*pv.w;
        d = waveReduceSum(d);
        if (l == 0){
            float2 ab = pab[cand];
            sv[w*4 + c] = d * fminf(qa * ab.x, qb * ab.y);
            sx[w*4 + c] = cand;
        }
    }
    __syncthreads();
    if (tid == 0){
        for (int k = 0; k < 7; ++k){
            float best = -INFINITY; int bi = 0x7FFFFFFF; int bj = 0;
            for (int j = 0; j < 16; ++j){
                float v = sv[j]; int x = sx[j];
                if (v > best || (v == best && x < bi)){ best = v; bi = x; bj = j; }
            }
            fi[n*7 + k] = bi;
            sv[bj] = -INFINITY;
        }
    }
}

// ---- gather demos, h = demos @ W, GCN chain, fused, anomaly score ----
__launch_bounds__(256, 4)
__global__ void fusion(const float* __restrict__ qemb, const float* __restrict__ pool,
                       const float* __restrict__ W, const float* __restrict__ b,
                       const float* __restrict__ qn, const int* __restrict__ fi,
                       float* __restrict__ out){
    __shared__ float dem[7][256];
    __shared__ float red[3][4];
    __shared__ int   sidx[7];
    int n = blockIdx.x, tid = threadIdx.x;
    if (tid < 7) sidx[tid] = fi[n*7 + tid];
    __syncthreads();
    #pragma unroll
    for (int k = 0; k < 7; ++k)
        dem[k][tid] = pool[(size_t)sidx[k] * D_ + tid];
    __syncthreads();

    float h[7];
    #pragma unroll
    for (int k = 0; k < 7; ++k) h[k] = 0.0f;
    for (int e = 0; e < D_; ++e){
        float w = W[(size_t)e * D_ + tid];
        #pragma unroll
        for (int k = 0; k < 7; ++k) h[k] = fmaf(dem[k][e], w, h[k]);
    }
    const float c0 = 1.0f + 0.70710678f;
    float fused = h[0]*c0 + h[1] + h[2] + h[3] + h[4] + h[5] + h[6]*0.5f;
    fused = fused * (1.0f / 7.0f) + b[tid];

    float qn_d = qn[(size_t)n * D_ + tid];
    float q_d  = qemb[(size_t)n * D_ + tid];
    float s_ff = fused * fused;
    float s_qf = qn_d * fused;
    float dq   = q_d - fused;
    float s_dd = dq * dq;
    s_ff = waveReduceSum(s_ff);
    s_qf = waveReduceSum(s_qf);
    s_dd = waveReduceSum(s_dd);
    int wv = tid >> 6, ln = tid & 63;
    if (ln == 0){ red[0][wv] = s_ff; red[1][wv] = s_qf; red[2][wv] = s_dd; }
    __syncthreads();
    if (tid == 0){
        float ff  = red[0][0] + red[0][1] + red[0][2] + red[0][3];
        float qf  = red[1][0] + red[1][1] + red[1][2] + red[1][3];
        float dd2 = red[2][0] + red[2][1] + red[2][2] + red[2][3];
        float cosv = qf / fmaxf(sqrtf(ff), EPSN);
        float l2   = sqrtf(dd2);
        out[n] = 0.6f * (1.0f - cosv) + 0.4f * l2;
    }
}

extern "C" void kernel_launch(void* const* d_in, const int* in_sizes, int n_in,
                              void* d_out, int out_size, void* d_ws, size_t ws_size,
                              hipStream_t stream){
    const float* qemb  = (const float*)d_in[0];
    const float* qtime = (const float*)d_in[1];
    const float* pool  = (const float*)d_in[2];
    const float* ptime = (const float*)d_in[3];
    const float* lam   = (const float*)d_in[4];
    const float* W     = (const float*)d_in[5];
    const float* b     = (const float*)d_in[6];
    float* out = (float*)d_out;
    char* wsb = (char*)d_ws;

    float*    qn    = (float*)   (wsb + OFF_QN);
    float*    qa    = (float*)   (wsb + OFF_QA);
    float*    qb    = (float*)   (wsb + OFF_QB);
    float*    pab   = (float*)   (wsb + OFF_PAB);
    ushort_t* qnb   = (ushort_t*)(wsb + OFF_QNB);
    ushort_t* poolb = (ushort_t*)(wsb + OFF_PB16);
    uint_t*   ck    = (uint_t*)  (wsb + OFF_CK);
    int*      ci    = (int*)     (wsb + OFF_CI);
    int*      c16   = (int*)     (wsb + OFF_C16);
    int*      fi    = (int*)     (wsb + OFF_FI);

    prep_query<<<N_Q / 4, 256, 0, stream>>>(qemb, qtime, lam, qn, qnb, qa, qb);
    prep_pool<<<M_P / 4, 256, 0, stream>>>(pool, ptime, lam, pab, poolb);
    scores_mfma<<<512, 256, 0, stream>>>(poolb, qnb, pab, qa, qb, ck, ci);
    merge_global<<<4, 256, 0, stream>>>(ck, ci, c16);
    rerank<<<N_Q, 256, 0, stream>>>(pool, qn, pab, qa, qb, c16, fi);
    fusion<<<N_Q, 256, 0, stream>>>(qemb, pool, W, b, qn, fi, out);
}